// Round 17
// baseline (177.989 us; speedup 1.0000x reference)
//
#include <hip/hip_runtime.h>
#include <hip/hip_bf16.h>

// MSSA: x(8,2048,512) -> qkv = x@Wqkv ; scores = (q*s)@(k*s)^T over FULL 512 dims ;
// attn = softmax ; out = attn@v ; result = (out + x)@Wout + bout
//
// R17 = R16 with sgemm rebuilt as the pv-structure (one change):
//  - sgemm128: 128x128, BK=64, dbuf stage-early, T2 swizzle, 64KB LDS ->
//    2 blocks/CU, grid 2048. R16 evidence: pv (same body, 2 blocks/CU) = 765 TF
//    vs sgemm 256^2 (1 block/CU) = 560 TF -- co-residency covers barrier drains.
//    Epilogue partials layout = R11-proven part[row*32 + kvt*2 + wc].
//  - gemm_qkv97: q/k -> qkvb, v -> VT directly (R15/R16). prep_x bf16 (R16).
//  - pvgemm97 / gemm_out97 / combine_l / prep_w / transpose_wout frozen.
//
// Workspace (128 MiB): qkvb 50.3 | VT 16.8 | S 67.1 (pre-sgemm: xb+WT alias S;
// post-pvgemm: WoutT aliases dead S).
// LESSONS: R3/R4 512-thr regs cap 256/wave. R9 exp off PV K-loop. R10/R11/R14
// schedule ports neutral. R12 BK64 linear LDS = 16-way; R13 swizzle -> 0 conflicts.
// R15 fp32-A fusion bad. R16: 1-block/CU 256^2 loses to 2-block/CU 128^2.

typedef __attribute__((ext_vector_type(8))) short bf16x8;
typedef __attribute__((ext_vector_type(4))) float f32x4;
typedef __attribute__((ext_vector_type(4))) unsigned short u16x4;

__device__ __forceinline__ unsigned short f2bf(float f) {
  unsigned u = __builtin_bit_cast(unsigned, f);
  u += 0x7fffu + ((u >> 16) & 1u);   // RNE
  return (unsigned short)(u >> 16);
}
__device__ __forceinline__ float bf2f(unsigned short h) {
  unsigned u = ((unsigned)h) << 16;
  return __builtin_bit_cast(float, u);
}

// async global->LDS, 16B/lane; LDS dest = wave-uniform base + lane*16 (HW rule)
__device__ __forceinline__ void async16(const unsigned short* g, unsigned short* l) {
  __builtin_amdgcn_global_load_lds(
      (const __attribute__((address_space(1))) unsigned int*)g,
      (__attribute__((address_space(3))) unsigned int*)l, 16, 0, 0);
}

// ---------------- prep_x: xb = bf16(X) ----------------
__global__ __launch_bounds__(256) void prep_x(const float* __restrict__ X,
                                              unsigned short* __restrict__ XB) {
  const size_t base = ((size_t)blockIdx.x * 256 + threadIdx.x) * 16;
  f32x4 a0 = *(const f32x4*)&X[base];
  f32x4 a1 = *(const f32x4*)&X[base + 4];
  f32x4 a2 = *(const f32x4*)&X[base + 8];
  f32x4 a3 = *(const f32x4*)&X[base + 12];
  bf16x8 o0, o1;
#pragma unroll
  for (int j = 0; j < 4; ++j) {
    o0[j] = (short)f2bf(a0[j]);
    o0[4 + j] = (short)f2bf(a1[j]);
    o1[j] = (short)f2bf(a2[j]);
    o1[4 + j] = (short)f2bf(a3[j]);
  }
  *(bf16x8*)&XB[base] = o0;
  *(bf16x8*)&XB[base + 8] = o1;
}

// ---------------- prep_w: WT[c][k] = bf16(Wqkv[k][c] * (c<1024 ? 0.125 : 1)) ----------------
__global__ __launch_bounds__(256) void prep_w(const float* __restrict__ W,
                                              unsigned short* __restrict__ WT) {
  const int t = threadIdx.x;
  const int c0 = blockIdx.x * 128 + (t & 15) * 8;
  const int k0 = blockIdx.y * 128 + (t >> 4) * 8;
  float r[8][8];
#pragma unroll
  for (int j = 0; j < 8; ++j) {
    f32x4 lo = *(const f32x4*)&W[(size_t)(k0 + j) * 1536 + c0];
    f32x4 hi = *(const f32x4*)&W[(size_t)(k0 + j) * 1536 + c0 + 4];
#pragma unroll
    for (int q = 0; q < 4; ++q) {
      r[j][q] = lo[q];
      r[j][4 + q] = hi[q];
    }
  }
#pragma unroll
  for (int i = 0; i < 8; ++i) {
    const float scl = (c0 + i < 1024) ? 0.125f : 1.0f;
    bf16x8 o;
#pragma unroll
    for (int j = 0; j < 8; ++j) o[j] = (short)f2bf(r[j][i] * scl);
    *(bf16x8*)&WT[(size_t)(c0 + i) * 512 + k0] = o;
  }
}

// ---------------- transpose_wout: WoutT[c][k] = bf16(Wout[k][c]) ----------------
__global__ __launch_bounds__(256) void transpose_wout(const float* __restrict__ W,
                                                      unsigned short* __restrict__ WT) {
  const int t = threadIdx.x;
  const int c0 = blockIdx.x * 128 + (t & 15) * 8;
  const int k0 = blockIdx.y * 128 + (t >> 4) * 8;
  float r[8][8];
#pragma unroll
  for (int j = 0; j < 8; ++j) {
    f32x4 lo = *(const f32x4*)&W[(size_t)(k0 + j) * 512 + c0];
    f32x4 hi = *(const f32x4*)&W[(size_t)(k0 + j) * 512 + c0 + 4];
#pragma unroll
    for (int q = 0; q < 4; ++q) {
      r[j][q] = lo[q];
      r[j][4 + q] = hi[q];
    }
  }
#pragma unroll
  for (int i = 0; i < 8; ++i) {
    bf16x8 o;
#pragma unroll
    for (int j = 0; j < 8; ++j) o[j] = (short)f2bf(r[j][i]);
    *(bf16x8*)&WT[(size_t)(c0 + i) * 512 + k0] = o;
  }
}

#define GEMM97_VARS                                            \
  const int tid = threadIdx.x;                                 \
  const int wave = tid >> 6, lane = tid & 63;                  \
  const int wr = wave >> 1, wc = wave & 1;                     \
  const int lg = lane >> 4, ll = lane & 15;                    \
  const int kk = lg * 8;                                       \
  const int srow = wave * 32 + (lane >> 2);                    \
  const int scol = (lane & 3) * 8;

// ======== GEMM1: qkv = xb @ WT^T (R8/R13 body); q/k -> qkvb, v -> VT directly ========
__global__ __launch_bounds__(256, 3) void gemm_qkv97(const unsigned short* __restrict__ XB,
                                                     const unsigned short* __restrict__ WT,
                                                     unsigned short* __restrict__ QKV,
                                                     unsigned short* __restrict__ VT) {
  __shared__ __align__(16) unsigned short Asm[4096];
  __shared__ __align__(16) unsigned short Bsm[4096];
  GEMM97_VARS
  const int bid = blockIdx.x;
  const int qt = bid / 12, nt = bid - qt * 12;
  const unsigned short* Ag = XB + (size_t)(qt * 128) * 512;
  const unsigned short* Bg = WT + (size_t)(nt * 128) * 512;
  f32x4 acc[4][4];
#pragma unroll
  for (int i = 0; i < 4; ++i)
#pragma unroll
    for (int j = 0; j < 4; ++j) acc[i][j] = (f32x4){0.f, 0.f, 0.f, 0.f};
  for (int kt = 0; kt < 512; kt += 32) {
    async16(&Ag[(size_t)srow * 512 + kt + scol], &Asm[wave * 1024]);
    async16(&Ag[(size_t)(srow + 16) * 512 + kt + scol], &Asm[wave * 1024 + 512]);
    async16(&Bg[(size_t)srow * 512 + kt + scol], &Bsm[wave * 1024]);
    async16(&Bg[(size_t)(srow + 16) * 512 + kt + scol], &Bsm[wave * 1024 + 512]);
    __syncthreads();
    bf16x8 af[4], bfr[4];
#pragma unroll
    for (int ai = 0; ai < 4; ++ai) af[ai] = *(const bf16x8*)&Asm[(wr * 64 + ai * 16 + ll) * 32 + kk];
#pragma unroll
    for (int bj = 0; bj < 4; ++bj) bfr[bj] = *(const bf16x8*)&Bsm[(wc * 64 + bj * 16 + ll) * 32 + kk];
#pragma unroll
    for (int ai = 0; ai < 4; ++ai)
#pragma unroll
      for (int bj = 0; bj < 4; ++bj)
        acc[ai][bj] = __builtin_amdgcn_mfma_f32_16x16x32_bf16(af[ai], bfr[bj], acc[ai][bj], 0, 0, 0);
    __syncthreads();
  }
  if (nt < 8) {  // q/k columns -> qkvb (block-uniform branch)
#pragma unroll
    for (int ai = 0; ai < 4; ++ai)
#pragma unroll
      for (int bj = 0; bj < 4; ++bj) {
        const int col = nt * 128 + wc * 64 + bj * 16 + ll;
#pragma unroll
        for (int r = 0; r < 4; ++r) {
          const int row = qt * 128 + wr * 64 + ai * 16 + lg * 4 + r;
          QKV[(size_t)row * 1536 + col] = f2bf(acc[ai][bj][r]);
        }
      }
  } else {  // v columns -> VT[d][m] directly (r-rows contiguous -> packed u16x4)
#pragma unroll
    for (int ai = 0; ai < 4; ++ai)
#pragma unroll
      for (int bj = 0; bj < 4; ++bj) {
        const int d = (nt - 8) * 128 + wc * 64 + bj * 16 + ll;
        const int row0 = qt * 128 + wr * 64 + ai * 16 + lg * 4;
        u16x4 o;
#pragma unroll
        for (int r = 0; r < 4; ++r) o[r] = f2bf(acc[ai][bj][r]);
        *(u16x4*)&VT[(size_t)d * 16384 + row0] = o;
      }
  }
}

// ======== sgemm128: 128x128, BK=64, dbuf, stage-early, T2-swizzled (pv-structure) ========
// grid 2048 (8 batch x 16 qt x 16 kvt), 2 blocks/CU. Epilogue: exp + partials.
__global__ __launch_bounds__(256, 3) void sgemm128(const unsigned short* __restrict__ QKV,
                                                   unsigned short* __restrict__ S,
                                                   float* __restrict__ part) {
  __shared__ __align__(16) unsigned short Asm[2][8192];  // [buf][128*64]
  __shared__ __align__(16) unsigned short Bsm[2][8192];
  const int tid = threadIdx.x;
  const int wave = tid >> 6, lane = tid & 63;
  const int wr = wave >> 1, wc = wave & 1;
  const int lg = lane >> 4, ll = lane & 15;
  const int bid = blockIdx.x;
  const int b = bid & 7;  // batch -> XCD
  const int idx = bid >> 3;
  const int kvt = idx & 15, qt = idx >> 4;
  const unsigned short* Ag = QKV + ((size_t)b * 2048 + qt * 128) * 1536;
  const unsigned short* Bg = QKV + ((size_t)b * 2048 + kvt * 128) * 1536 + 512;
  const int sr = wave * 32 + (lane >> 3);                 // +8*i
  const int sc = (((lane & 7) ^ ((lane >> 3) & 7))) * 8;  // PRE-SWIZZLED source col

  f32x4 acc[4][4];
#pragma unroll
  for (int i = 0; i < 4; ++i)
#pragma unroll
    for (int j = 0; j < 4; ++j) acc[i][j] = (f32x4){0.f, 0.f, 0.f, 0.f};

#define SG_STAGE(BUF, KT)                                                                   \
  _Pragma("unroll") for (int i = 0; i < 4; ++i) {                                           \
    async16(&Ag[(size_t)(sr + i * 8) * 1536 + (KT) + sc], &Asm[BUF][(wave * 32 + i * 8) * 64]);  \
    async16(&Bg[(size_t)(sr + i * 8) * 1536 + (KT) + sc], &Bsm[BUF][(wave * 32 + i * 8) * 64]);  \
  }

  SG_STAGE(0, 0)
  int cur = 0;
  __syncthreads();
  for (int kt = 0; kt < 512; kt += 64) {
    if (kt + 64 < 512) {
      if (cur) { SG_STAGE(0, kt + 64) } else { SG_STAGE(1, kt + 64) }
    }
#pragma unroll
    for (int half = 0; half < 2; ++half) {
      const int kb = (((half * 4 + lg) ^ (ll & 7))) * 8;  // swizzled read col
      bf16x8 af[4], bf4[4];
#pragma unroll
      for (int ai = 0; ai < 4; ++ai)
        af[ai] = *(const bf16x8*)&Asm[cur][(wr * 64 + ai * 16 + ll) * 64 + kb];
#pragma unroll
      for (int bj = 0; bj < 4; ++bj)
        bf4[bj] = *(const bf16x8*)&Bsm[cur][(wc * 64 + bj * 16 + ll) * 64 + kb];
#pragma unroll
      for (int ai = 0; ai < 4; ++ai)
#pragma unroll
        for (int bj = 0; bj < 4; ++bj)
          acc[ai][bj] = __builtin_amdgcn_mfma_f32_16x16x32_bf16(af[ai], bf4[bj], acc[ai][bj], 0, 0, 0);
    }
    __syncthreads();
    cur ^= 1;
  }
#undef SG_STAGE

  // exp (max-free) + per-(row, kvt, wc) partial sums (R11-proven layout)
#pragma unroll
  for (int ai = 0; ai < 4; ++ai)
#pragma unroll
    for (int bj = 0; bj < 4; ++bj)
#pragma unroll
      for (int r = 0; r < 4; ++r) acc[ai][bj][r] = __expf(acc[ai][bj][r]);

#pragma unroll
  for (int ai = 0; ai < 4; ++ai)
#pragma unroll
    for (int r = 0; r < 4; ++r) {
      float se = (acc[ai][0][r] + acc[ai][1][r]) + (acc[ai][2][r] + acc[ai][3][r]);
      se += __shfl_xor(se, 1);
      se += __shfl_xor(se, 2);
      se += __shfl_xor(se, 4);
      se += __shfl_xor(se, 8);
      if (ll == 0) {
        const size_t rowg = (size_t)b * 2048 + qt * 128 + wr * 64 + ai * 16 + lg * 4 + r;
        part[rowg * 32 + kvt * 2 + wc] = se;
      }
    }

  unsigned short* Sg = S + (size_t)b * 2048 * 2048;
#pragma unroll
  for (int ai = 0; ai < 4; ++ai)
#pragma unroll
    for (int bj = 0; bj < 4; ++bj) {
      const int col = kvt * 128 + wc * 64 + bj * 16 + ll;
#pragma unroll
      for (int r = 0; r < 4; ++r) {
        const int row = qt * 128 + wr * 64 + ai * 16 + lg * 4 + r;
        Sg[(size_t)row * 2048 + col] = f2bf(acc[ai][bj][r]);
      }
    }
}

// fold 32 per-(tile,half) sums -> per-row 1/l
__global__ __launch_bounds__(256) void combine_l(const float* __restrict__ part,
                                                 float* __restrict__ invl) {
  const int row = blockIdx.x * 256 + threadIdx.x;
  float l = 0.f;
#pragma unroll
  for (int t = 0; t < 8; ++t) {
    f32x4 v = *(const f32x4*)&part[(size_t)row * 32 + t * 4];
    l += (v[0] + v[1]) + (v[2] + v[3]);
  }
  invl[row] = 1.0f / l;
}

// res = (P~ @ V) * invl + x  -- 128x128, BK=64, dbuf, stage-early, T2-swizzled (R13)
__global__ __launch_bounds__(256, 3) void pvgemm97(const unsigned short* __restrict__ S,
                                                   const unsigned short* __restrict__ VT,
                                                   const float* __restrict__ X,
                                                   const float* __restrict__ invl,
                                                   unsigned short* __restrict__ RES) {
  __shared__ __align__(16) unsigned short Asm[2][8192];  // [buf][128*64]
  __shared__ __align__(16) unsigned short Bsm[2][8192];
  const int tid = threadIdx.x;
  const int wave = tid >> 6, lane = tid & 63;
  const int wr = wave >> 1, wc = wave & 1;
  const int lg = lane >> 4, ll = lane & 15;
  const int bid = blockIdx.x;
  const int b = bid & 7;
  const int idx = bid >> 3;
  const int dt = idx & 3, qt = idx >> 2;
  const unsigned short* Ag = S + (size_t)b * 2048 * 2048 + (size_t)(qt * 128) * 2048;
  const unsigned short* Bg = VT + (size_t)(dt * 128) * 16384 + (size_t)b * 2048;
  const int sr = wave * 32 + (lane >> 3);                 // +8*i
  const int sc = (((lane & 7) ^ ((lane >> 3) & 7))) * 8;  // PRE-SWIZZLED source col

  f32x4 acc[4][4];
#pragma unroll
  for (int i = 0; i < 4; ++i)
#pragma unroll
    for (int j = 0; j < 4; ++j) acc[i][j] = (f32x4){0.f, 0.f, 0.f, 0.f};

#define PV_STAGE(BUF, KT)                                                                   \
  _Pragma("unroll") for (int i = 0; i < 4; ++i) {                                           \
    async16(&Ag[(size_t)(sr + i * 8) * 2048 + (KT) + sc], &Asm[BUF][(wave * 32 + i * 8) * 64]);  \
    async16(&Bg[(size_t)(sr + i * 8) * 16384 + (KT) + sc], &Bsm[BUF][(wave * 32 + i * 8) * 64]); \
  }

  PV_STAGE(0, 0)
  int cur = 0;
  __syncthreads();
  for (int kt = 0; kt < 2048; kt += 64) {
    if (kt + 64 < 2048) {
      if (cur) { PV_STAGE(0, kt + 64) } else { PV_STAGE(1, kt + 64) }
    }
#pragma unroll
    for (int half = 0; half < 2; ++half) {
      const int kb = (((half * 4 + lg) ^ (ll & 7))) * 8;  // swizzled read col
      bf16x8 af[4], bf4[4];
#pragma unroll
      for (int ai = 0; ai < 4; ++ai)
        af[ai] = *(const bf16x8*)&Asm[cur][(wr * 64 + ai * 16 + ll) * 64 + kb];
#pragma unroll
      for (int bj = 0; bj < 4; ++bj)
        bf4[bj] = *(const bf16x8*)&Bsm[cur][(wc * 64 + bj * 16 + ll) * 64 + kb];
#pragma unroll
      for (int ai = 0; ai < 4; ++ai)
#pragma unroll
        for (int bj = 0; bj < 4; ++bj)
          acc[ai][bj] = __builtin_amdgcn_mfma_f32_16x16x32_bf16(af[ai], bf4[bj], acc[ai][bj], 0, 0, 0);
    }
    __syncthreads();
    cur ^= 1;
  }
#undef PV_STAGE

  const int rowbase = b * 2048 + qt * 128 + wr * 64;
  float il[4][4];
#pragma unroll
  for (int ai = 0; ai < 4; ++ai)
#pragma unroll
    for (int r = 0; r < 4; ++r) il[ai][r] = invl[rowbase + ai * 16 + lg * 4 + r];
#pragma unroll
  for (int ai = 0; ai < 4; ++ai)
#pragma unroll
    for (int bj = 0; bj < 4; ++bj) {
      const int col = dt * 128 + wc * 64 + bj * 16 + ll;
#pragma unroll
      for (int r = 0; r < 4; ++r) {
        const size_t row = (size_t)rowbase + ai * 16 + lg * 4 + r;
        const float val = acc[ai][bj][r] * il[ai][r] + X[row * 512 + col];
        RES[row * 1536 + 1024 + col] = f2bf(val);
      }
    }
}

// out = res @ WoutT^T + bout (fp32 out) -- R8 single-buf body
__global__ __launch_bounds__(256, 3) void gemm_out97(const unsigned short* __restrict__ A,
                                                     const unsigned short* __restrict__ WT,
                                                     const float* __restrict__ bias,
                                                     float* __restrict__ OUT) {
  __shared__ __align__(16) unsigned short Asm[4096];
  __shared__ __align__(16) unsigned short Bsm[4096];
  GEMM97_VARS
  const int bid = blockIdx.x;
  const int dt = bid & 3, qt = bid >> 2;
  const unsigned short* Ag = A + (size_t)(qt * 128) * 1536 + 1024;
  const unsigned short* Bg = WT + (size_t)(dt * 128) * 512;
  f32x4 acc[4][4];
#pragma unroll
  for (int i = 0; i < 4; ++i)
#pragma unroll
    for (int j = 0; j < 4; ++j) acc[i][j] = (f32x4){0.f, 0.f, 0.f, 0.f};
  for (int kt = 0; kt < 512; kt += 32) {
    async16(&Ag[(size_t)srow * 1536 + kt + scol], &Asm[wave * 1024]);
    async16(&Ag[(size_t)(srow + 16) * 1536 + kt + scol], &Asm[wave * 1024 + 512]);
    async16(&Bg[(size_t)srow * 512 + kt + scol], &Bsm[wave * 1024]);
    async16(&Bg[(size_t)(srow + 16) * 512 + kt + scol], &Bsm[wave * 1024 + 512]);
    __syncthreads();
    bf16x8 af[4], bfr[4];
#pragma unroll
    for (int ai = 0; ai < 4; ++ai) af[ai] = *(const bf16x8*)&Asm[(wr * 64 + ai * 16 + ll) * 32 + kk];
#pragma unroll
    for (int bj = 0; bj < 4; ++bj) bfr[bj] = *(const bf16x8*)&Bsm[(wc * 64 + bj * 16 + ll) * 32 + kk];
#pragma unroll
    for (int ai = 0; ai < 4; ++ai)
#pragma unroll
      for (int bj = 0; bj < 4; ++bj)
        acc[ai][bj] = __builtin_amdgcn_mfma_f32_16x16x32_bf16(af[ai], bfr[bj], acc[ai][bj], 0, 0, 0);
    __syncthreads();
  }
#pragma unroll
  for (int ai = 0; ai < 4; ++ai)
#pragma unroll
    for (int bj = 0; bj < 4; ++bj) {
      const int col = dt * 128 + wc * 64 + bj * 16 + ll;
      const float bv = bias[col];
#pragma unroll
      for (int r = 0; r < 4; ++r) {
        const int row = qt * 128 + wr * 64 + ai * 16 + lg * 4 + r;
        OUT[(size_t)row * 512 + col] = acc[ai][bj][r] + bv;
      }
    }
}

extern "C" void kernel_launch(void* const* d_in, const int* in_sizes, int n_in,
                              void* d_out, int out_size, void* d_ws, size_t ws_size,
                              hipStream_t stream) {
  const float* x = (const float*)d_in[0];     // [8,2048,512]
  const float* Wqkv = (const float*)d_in[1];  // [512,1536]
  const float* Wout = (const float*)d_in[2];  // [512,512]
  const float* bout = (const float*)d_in[3];  // [512]
  float* out = (float*)d_out;                 // [8,2048,512] fp32

  unsigned short* qkvb = (unsigned short*)d_ws;        // 16384*1536 bf16 (q/k cols used)
  unsigned short* VT = qkvb + (size_t)16384 * 1536;    // 512*16384 bf16 = 16.8MB
  unsigned short* S = VT + (size_t)512 * 16384;        // 8*2048*2048 bf16 = 67.1MB
  unsigned short* xb = S;                              // bf16 X (dead before sgemm)
  unsigned short* WT = S + (size_t)16384 * 512;        // Wqkv^T scaled (dead before sgemm)
  // WoutT: written into dead S start after pvgemm (R15-validated ordering)
  float* part = out;                                   // [16384][32] f32 = 2MB
  float* invl = out + (size_t)16384 * 32;              // [16384] f32 = 64KB

  prep_x<<<2048, 256, 0, stream>>>(x, xb);
  prep_w<<<dim3(12, 4), 256, 0, stream>>>(Wqkv, WT);
  gemm_qkv97<<<1536, 256, 0, stream>>>(xb, WT, qkvb, VT);
  sgemm128<<<2048, 256, 0, stream>>>(qkvb, S, part);
  combine_l<<<64, 256, 0, stream>>>(part, invl);
  pvgemm97<<<512, 256, 0, stream>>>(S, VT, x, invl, qkvb);
  transpose_wout<<<dim3(4, 4), 256, 0, stream>>>(Wout, (unsigned short*)S);  // S dead now
  gemm_out97<<<512, 256, 0, stream>>>(qkvb, (unsigned short*)S, bout, out);
}

// Round 18
// 168.689 us; speedup vs baseline: 1.0551x; 1.0551x over previous
//
#include <hip/hip_runtime.h>
#include <hip/hip_bf16.h>

// MSSA: x(8,2048,512) -> qkv = x@Wqkv ; scores = (q*s)@(k*s)^T over FULL 512 dims ;
// attn = softmax ; out = attn@v ; result = (out + x)@Wout + bout
//
// R18 = consolidation to best-known-good + overhead removal:
//  - sgemm: R16 256x256 body restored (61us proven; R17's 128^2 = 67us: co-residency
//    theory WRONG -- both give 8 waves/CU; 128^2 just re-reads panels 2x).
//  - combine_l folded into pvgemm prologue (invl computed per-block into LDS under
//    the first stage's async latency) -- dispatch deleted.
//  - prep_x + prep_w merged into one kernel -- dispatch deleted.
//  - gemm_qkv97 (q/k->qkvb, v->VT direct), pvgemm97, gemm_out97, transpose_wout:
//    frozen R16 bodies.
//  - Max-free fused softmax: sgemm epilogue exp + partial sums -> part (d_out
//    scratch); pv computes invl locally; pv epilogue acc*invl + x.
//
// Workspace (128 MiB): qkvb 50.3 | VT 16.8 | S 67.1 (pre-sgemm: xb+WT alias S;
// post-pvgemm: WoutT aliases dead S).
// LESSONS: R3/R4 512-thr regs cap 256/wave. R9 exp off PV K-loop. R10/R11/R14
// schedule ports neutral-or-negative; 2-phase stage-early is this family's optimum.
// R12 BK64 linear LDS = 16-way conflict; R13 swizzle -> 0. R15 fp32-A fusion bad.
// R16/R17: 8 waves/CU either way; K-loop length is what separates 560 vs 765 TF.

typedef __attribute__((ext_vector_type(8))) short bf16x8;
typedef __attribute__((ext_vector_type(4))) float f32x4;
typedef __attribute__((ext_vector_type(4))) unsigned short u16x4;

__device__ __forceinline__ unsigned short f2bf(float f) {
  unsigned u = __builtin_bit_cast(unsigned, f);
  u += 0x7fffu + ((u >> 16) & 1u);   // RNE
  return (unsigned short)(u >> 16);
}
__device__ __forceinline__ float bf2f(unsigned short h) {
  unsigned u = ((unsigned)h) << 16;
  return __builtin_bit_cast(float, u);
}

// async global->LDS, 16B/lane; LDS dest = wave-uniform base + lane*16 (HW rule)
__device__ __forceinline__ void async16(const unsigned short* g, unsigned short* l) {
  __builtin_amdgcn_global_load_lds(
      (const __attribute__((address_space(1))) unsigned int*)g,
      (__attribute__((address_space(3))) unsigned int*)l, 16, 0, 0);
}

// ---------------- prep_xw: blocks <2048: xb = bf16(X); blocks >=2048: WT prep ----------------
__global__ __launch_bounds__(256) void prep_xw(const float* __restrict__ X,
                                               unsigned short* __restrict__ XB,
                                               const float* __restrict__ W,
                                               unsigned short* __restrict__ WT) {
  const int t = threadIdx.x;
  if (blockIdx.x < 2048) {  // xb = bf16(X)
    const size_t base = ((size_t)blockIdx.x * 256 + t) * 16;
    f32x4 a0 = *(const f32x4*)&X[base];
    f32x4 a1 = *(const f32x4*)&X[base + 4];
    f32x4 a2 = *(const f32x4*)&X[base + 8];
    f32x4 a3 = *(const f32x4*)&X[base + 12];
    bf16x8 o0, o1;
#pragma unroll
    for (int j = 0; j < 4; ++j) {
      o0[j] = (short)f2bf(a0[j]);
      o0[4 + j] = (short)f2bf(a1[j]);
      o1[j] = (short)f2bf(a2[j]);
      o1[4 + j] = (short)f2bf(a3[j]);
    }
    *(bf16x8*)&XB[base] = o0;
    *(bf16x8*)&XB[base + 8] = o1;
  } else {  // WT[c][k] = bf16(Wqkv[k][c] * (c<1024 ? 0.125 : 1))
    const int bid2 = blockIdx.x - 2048;            // 48 blocks: 12 c-tiles x 4 k-tiles
    const int c0 = (bid2 % 12) * 128 + (t & 15) * 8;
    const int k0 = (bid2 / 12) * 128 + (t >> 4) * 8;
    float r[8][8];
#pragma unroll
    for (int j = 0; j < 8; ++j) {
      f32x4 lo = *(const f32x4*)&W[(size_t)(k0 + j) * 1536 + c0];
      f32x4 hi = *(const f32x4*)&W[(size_t)(k0 + j) * 1536 + c0 + 4];
#pragma unroll
      for (int q = 0; q < 4; ++q) {
        r[j][q] = lo[q];
        r[j][4 + q] = hi[q];
      }
    }
#pragma unroll
    for (int i = 0; i < 8; ++i) {
      const float scl = (c0 + i < 1024) ? 0.125f : 1.0f;
      bf16x8 o;
#pragma unroll
      for (int j = 0; j < 8; ++j) o[j] = (short)f2bf(r[j][i] * scl);
      *(bf16x8*)&WT[(size_t)(c0 + i) * 512 + k0] = o;
    }
  }
}

// ---------------- transpose_wout: WoutT[c][k] = bf16(Wout[k][c]) ----------------
__global__ __launch_bounds__(256) void transpose_wout(const float* __restrict__ W,
                                                      unsigned short* __restrict__ WT) {
  const int t = threadIdx.x;
  const int c0 = blockIdx.x * 128 + (t & 15) * 8;
  const int k0 = blockIdx.y * 128 + (t >> 4) * 8;
  float r[8][8];
#pragma unroll
  for (int j = 0; j < 8; ++j) {
    f32x4 lo = *(const f32x4*)&W[(size_t)(k0 + j) * 512 + c0];
    f32x4 hi = *(const f32x4*)&W[(size_t)(k0 + j) * 512 + c0 + 4];
#pragma unroll
    for (int q = 0; q < 4; ++q) {
      r[j][q] = lo[q];
      r[j][4 + q] = hi[q];
    }
  }
#pragma unroll
  for (int i = 0; i < 8; ++i) {
    bf16x8 o;
#pragma unroll
    for (int j = 0; j < 8; ++j) o[j] = (short)f2bf(r[j][i]);
    *(bf16x8*)&WT[(size_t)(c0 + i) * 512 + k0] = o;
  }
}

#define GEMM97_VARS                                            \
  const int tid = threadIdx.x;                                 \
  const int wave = tid >> 6, lane = tid & 63;                  \
  const int wr = wave >> 1, wc = wave & 1;                     \
  const int lg = lane >> 4, ll = lane & 15;                    \
  const int kk = lg * 8;                                       \
  const int srow = wave * 32 + (lane >> 2);                    \
  const int scol = (lane & 3) * 8;

// ======== GEMM1: qkv = xb @ WT^T (R8/R13 body); q/k -> qkvb, v -> VT directly ========
__global__ __launch_bounds__(256, 3) void gemm_qkv97(const unsigned short* __restrict__ XB,
                                                     const unsigned short* __restrict__ WT,
                                                     unsigned short* __restrict__ QKV,
                                                     unsigned short* __restrict__ VT) {
  __shared__ __align__(16) unsigned short Asm[4096];
  __shared__ __align__(16) unsigned short Bsm[4096];
  GEMM97_VARS
  const int bid = blockIdx.x;
  const int qt = bid / 12, nt = bid - qt * 12;
  const unsigned short* Ag = XB + (size_t)(qt * 128) * 512;
  const unsigned short* Bg = WT + (size_t)(nt * 128) * 512;
  f32x4 acc[4][4];
#pragma unroll
  for (int i = 0; i < 4; ++i)
#pragma unroll
    for (int j = 0; j < 4; ++j) acc[i][j] = (f32x4){0.f, 0.f, 0.f, 0.f};
  for (int kt = 0; kt < 512; kt += 32) {
    async16(&Ag[(size_t)srow * 512 + kt + scol], &Asm[wave * 1024]);
    async16(&Ag[(size_t)(srow + 16) * 512 + kt + scol], &Asm[wave * 1024 + 512]);
    async16(&Bg[(size_t)srow * 512 + kt + scol], &Bsm[wave * 1024]);
    async16(&Bg[(size_t)(srow + 16) * 512 + kt + scol], &Bsm[wave * 1024 + 512]);
    __syncthreads();
    bf16x8 af[4], bfr[4];
#pragma unroll
    for (int ai = 0; ai < 4; ++ai) af[ai] = *(const bf16x8*)&Asm[(wr * 64 + ai * 16 + ll) * 32 + kk];
#pragma unroll
    for (int bj = 0; bj < 4; ++bj) bfr[bj] = *(const bf16x8*)&Bsm[(wc * 64 + bj * 16 + ll) * 32 + kk];
#pragma unroll
    for (int ai = 0; ai < 4; ++ai)
#pragma unroll
      for (int bj = 0; bj < 4; ++bj)
        acc[ai][bj] = __builtin_amdgcn_mfma_f32_16x16x32_bf16(af[ai], bfr[bj], acc[ai][bj], 0, 0, 0);
    __syncthreads();
  }
  if (nt < 8) {  // q/k columns -> qkvb (block-uniform branch)
#pragma unroll
    for (int ai = 0; ai < 4; ++ai)
#pragma unroll
      for (int bj = 0; bj < 4; ++bj) {
        const int col = nt * 128 + wc * 64 + bj * 16 + ll;
#pragma unroll
        for (int r = 0; r < 4; ++r) {
          const int row = qt * 128 + wr * 64 + ai * 16 + lg * 4 + r;
          QKV[(size_t)row * 1536 + col] = f2bf(acc[ai][bj][r]);
        }
      }
  } else {  // v columns -> VT[d][m] directly (r-rows contiguous -> packed u16x4)
#pragma unroll
    for (int ai = 0; ai < 4; ++ai)
#pragma unroll
      for (int bj = 0; bj < 4; ++bj) {
        const int d = (nt - 8) * 128 + wc * 64 + bj * 16 + ll;
        const int row0 = qt * 128 + wr * 64 + ai * 16 + lg * 4;
        u16x4 o;
#pragma unroll
        for (int r = 0; r < 4; ++r) o[r] = f2bf(acc[ai][bj][r]);
        *(u16x4*)&VT[(size_t)d * 16384 + row0] = o;
      }
  }
}

// ======== sgemm: 256x256, 8 waves, BK=64, dbuf, stage-early, T2-swizzled (R16) ========
__global__ __launch_bounds__(512) void sgemm256(const unsigned short* __restrict__ QKV,
                                                unsigned short* __restrict__ S,
                                                float* __restrict__ part) {
  __shared__ __align__(16) unsigned short Asm[2][16384];  // [buf][256*64]
  __shared__ __align__(16) unsigned short Bsm[2][16384];
  const int tid = threadIdx.x;
  const int wave = tid >> 6, lane = tid & 63;
  const int wr = wave >> 2, wc = wave & 3;
  const int lg = lane >> 4, ll = lane & 15;
  const int bid = blockIdx.x;
  const int b = bid & 7;  // batch -> XCD
  const int idx = bid >> 3;
  const int kvt = idx & 7, qt = idx >> 3;
  const unsigned short* Ag = QKV + ((size_t)b * 2048 + qt * 256) * 1536;
  const unsigned short* Bg = QKV + ((size_t)b * 2048 + kvt * 256) * 1536 + 512;
  const int sr = wave * 8 + (lane >> 3);                  // staging row (+64*i)
  const int sc = (((lane & 7) ^ ((lane >> 3) & 7))) * 8;  // PRE-SWIZZLED source col

  f32x4 acc[8][4];
#pragma unroll
  for (int i = 0; i < 8; ++i)
#pragma unroll
    for (int j = 0; j < 4; ++j) acc[i][j] = (f32x4){0.f, 0.f, 0.f, 0.f};

#define SG_STAGE(BUF, KT)                                                              \
  _Pragma("unroll") for (int i = 0; i < 4; ++i) {                                      \
    async16(&Ag[(size_t)(i * 64 + sr) * 1536 + (KT) + sc], &Asm[BUF][(i * 64 + wave * 8) * 64]); \
    async16(&Bg[(size_t)(i * 64 + sr) * 1536 + (KT) + sc], &Bsm[BUF][(i * 64 + wave * 8) * 64]); \
  }

  SG_STAGE(0, 0)
  int cur = 0;
  __syncthreads();
  for (int kt = 0; kt < 512; kt += 64) {
    if (kt + 64 < 512) {
      if (cur) { SG_STAGE(0, kt + 64) } else { SG_STAGE(1, kt + 64) }
    }
#pragma unroll
    for (int half = 0; half < 2; ++half) {
      const int kb = (((half * 4 + lg) ^ (ll & 7))) * 8;  // swizzled read col
      bf16x8 af[8], bf4[4];
#pragma unroll
      for (int ai = 0; ai < 8; ++ai)
        af[ai] = *(const bf16x8*)&Asm[cur][(wr * 128 + ai * 16 + ll) * 64 + kb];
#pragma unroll
      for (int bj = 0; bj < 4; ++bj)
        bf4[bj] = *(const bf16x8*)&Bsm[cur][(wc * 64 + bj * 16 + ll) * 64 + kb];
#pragma unroll
      for (int ai = 0; ai < 8; ++ai)
#pragma unroll
        for (int bj = 0; bj < 4; ++bj)
          acc[ai][bj] = __builtin_amdgcn_mfma_f32_16x16x32_bf16(af[ai], bf4[bj], acc[ai][bj], 0, 0, 0);
    }
    __syncthreads();  // drains next-tile asyncs + fences reads
    cur ^= 1;
  }
#undef SG_STAGE

  // exp (max-free) + per-(row, kvt, wc) partial sums over this wave's 64 cols
#pragma unroll
  for (int ai = 0; ai < 8; ++ai)
#pragma unroll
    for (int bj = 0; bj < 4; ++bj)
#pragma unroll
      for (int r = 0; r < 4; ++r) acc[ai][bj][r] = __expf(acc[ai][bj][r]);

#pragma unroll
  for (int ai = 0; ai < 8; ++ai)
#pragma unroll
    for (int r = 0; r < 4; ++r) {
      float se = (acc[ai][0][r] + acc[ai][1][r]) + (acc[ai][2][r] + acc[ai][3][r]);
      se += __shfl_xor(se, 1);
      se += __shfl_xor(se, 2);
      se += __shfl_xor(se, 4);
      se += __shfl_xor(se, 8);
      if (ll == 0) {
        const size_t rowg = (size_t)b * 2048 + qt * 256 + wr * 128 + ai * 16 + lg * 4 + r;
        part[rowg * 32 + kvt * 4 + wc] = se;
      }
    }

  unsigned short* Sg = S + (size_t)b * 2048 * 2048;
#pragma unroll
  for (int ai = 0; ai < 8; ++ai)
#pragma unroll
    for (int bj = 0; bj < 4; ++bj) {
      const int col = kvt * 256 + wc * 64 + bj * 16 + ll;
#pragma unroll
      for (int r = 0; r < 4; ++r) {
        const int row = qt * 256 + wr * 128 + ai * 16 + lg * 4 + r;
        Sg[(size_t)row * 2048 + col] = f2bf(acc[ai][bj][r]);
      }
    }
}

// res = (P~ @ V) * invl + x  -- 128x128, BK=64, dbuf, stage-early, T2-swizzled.
// invl computed in-block from part (combine_l folded in; hidden under first stage).
__global__ __launch_bounds__(256, 3) void pvgemm97(const unsigned short* __restrict__ S,
                                                   const unsigned short* __restrict__ VT,
                                                   const float* __restrict__ X,
                                                   const float* __restrict__ part,
                                                   unsigned short* __restrict__ RES) {
  __shared__ __align__(16) unsigned short Asm[2][8192];  // [buf][128*64]
  __shared__ __align__(16) unsigned short Bsm[2][8192];
  __shared__ float invl_s[128];
  const int tid = threadIdx.x;
  const int wave = tid >> 6, lane = tid & 63;
  const int wr = wave >> 1, wc = wave & 1;
  const int lg = lane >> 4, ll = lane & 15;
  const int bid = blockIdx.x;
  const int b = bid & 7;
  const int idx = bid >> 3;
  const int dt = idx & 3, qt = idx >> 2;
  const unsigned short* Ag = S + (size_t)b * 2048 * 2048 + (size_t)(qt * 128) * 2048;
  const unsigned short* Bg = VT + (size_t)(dt * 128) * 16384 + (size_t)b * 2048;
  const int sr = wave * 32 + (lane >> 3);                 // +8*i
  const int sc = (((lane & 7) ^ ((lane >> 3) & 7))) * 8;  // PRE-SWIZZLED source col

  f32x4 acc[4][4];
#pragma unroll
  for (int i = 0; i < 4; ++i)
#pragma unroll
    for (int j = 0; j < 4; ++j) acc[i][j] = (f32x4){0.f, 0.f, 0.f, 0.f};

#define PV_STAGE(BUF, KT)                                                                   \
  _Pragma("unroll") for (int i = 0; i < 4; ++i) {                                           \
    async16(&Ag[(size_t)(sr + i * 8) * 2048 + (KT) + sc], &Asm[BUF][(wave * 32 + i * 8) * 64]);  \
    async16(&Bg[(size_t)(sr + i * 8) * 16384 + (KT) + sc], &Bsm[BUF][(wave * 32 + i * 8) * 64]); \
  }

  PV_STAGE(0, 0)
  // fold combine_l: threads 0-127 reduce this q-panel's 32 partials -> 1/l in LDS
  if (tid < 128) {
    const size_t rowg = (size_t)b * 2048 + qt * 128 + tid;
    float l = 0.f;
#pragma unroll
    for (int t = 0; t < 8; ++t) {
      f32x4 v = *(const f32x4*)&part[rowg * 32 + t * 4];
      l += (v[0] + v[1]) + (v[2] + v[3]);
    }
    invl_s[tid] = 1.0f / l;
  }
  int cur = 0;
  __syncthreads();
  for (int kt = 0; kt < 2048; kt += 64) {
    if (kt + 64 < 2048) {
      if (cur) { PV_STAGE(0, kt + 64) } else { PV_STAGE(1, kt + 64) }
    }
#pragma unroll
    for (int half = 0; half < 2; ++half) {
      const int kb = (((half * 4 + lg) ^ (ll & 7))) * 8;  // swizzled read col
      bf16x8 af[4], bf4[4];
#pragma unroll
      for (int ai = 0; ai < 4; ++ai)
        af[ai] = *(const bf16x8*)&Asm[cur][(wr * 64 + ai * 16 + ll) * 64 + kb];
#pragma unroll
      for (int bj = 0; bj < 4; ++bj)
        bf4[bj] = *(const bf16x8*)&Bsm[cur][(wc * 64 + bj * 16 + ll) * 64 + kb];
#pragma unroll
      for (int ai = 0; ai < 4; ++ai)
#pragma unroll
        for (int bj = 0; bj < 4; ++bj)
          acc[ai][bj] = __builtin_amdgcn_mfma_f32_16x16x32_bf16(af[ai], bf4[bj], acc[ai][bj], 0, 0, 0);
    }
    __syncthreads();
    cur ^= 1;
  }
#undef PV_STAGE

  const int rowbase = b * 2048 + qt * 128 + wr * 64;
  float il[4][4];
#pragma unroll
  for (int ai = 0; ai < 4; ++ai)
#pragma unroll
    for (int r = 0; r < 4; ++r) il[ai][r] = invl_s[wr * 64 + ai * 16 + lg * 4 + r];
#pragma unroll
  for (int ai = 0; ai < 4; ++ai)
#pragma unroll
    for (int bj = 0; bj < 4; ++bj) {
      const int col = dt * 128 + wc * 64 + bj * 16 + ll;
#pragma unroll
      for (int r = 0; r < 4; ++r) {
        const size_t row = (size_t)rowbase + ai * 16 + lg * 4 + r;
        const float val = acc[ai][bj][r] * il[ai][r] + X[row * 512 + col];
        RES[row * 1536 + 1024 + col] = f2bf(val);
      }
    }
}

// out = res @ WoutT^T + bout (fp32 out) -- R8 single-buf body
__global__ __launch_bounds__(256, 3) void gemm_out97(const unsigned short* __restrict__ A,
                                                     const unsigned short* __restrict__ WT,
                                                     const float* __restrict__ bias,
                                                     float* __restrict__ OUT) {
  __shared__ __align__(16) unsigned short Asm[4096];
  __shared__ __align__(16) unsigned short Bsm[4096];
  GEMM97_VARS
  const int bid = blockIdx.x;
  const int dt = bid & 3, qt = bid >> 2;
  const unsigned short* Ag = A + (size_t)(qt * 128) * 1536 + 1024;
  const unsigned short* Bg = WT + (size_t)(dt * 128) * 512;
  f32x4 acc[4][4];
#pragma unroll
  for (int i = 0; i < 4; ++i)
#pragma unroll
    for (int j = 0; j < 4; ++j) acc[i][j] = (f32x4){0.f, 0.f, 0.f, 0.f};
  for (int kt = 0; kt < 512; kt += 32) {
    async16(&Ag[(size_t)srow * 1536 + kt + scol], &Asm[wave * 1024]);
    async16(&Ag[(size_t)(srow + 16) * 1536 + kt + scol], &Asm[wave * 1024 + 512]);
    async16(&Bg[(size_t)srow * 512 + kt + scol], &Bsm[wave * 1024]);
    async16(&Bg[(size_t)(srow + 16) * 512 + kt + scol], &Bsm[wave * 1024 + 512]);
    __syncthreads();
    bf16x8 af[4], bfr[4];
#pragma unroll
    for (int ai = 0; ai < 4; ++ai) af[ai] = *(const bf16x8*)&Asm[(wr * 64 + ai * 16 + ll) * 32 + kk];
#pragma unroll
    for (int bj = 0; bj < 4; ++bj) bfr[bj] = *(const bf16x8*)&Bsm[(wc * 64 + bj * 16 + ll) * 32 + kk];
#pragma unroll
    for (int ai = 0; ai < 4; ++ai)
#pragma unroll
      for (int bj = 0; bj < 4; ++bj)
        acc[ai][bj] = __builtin_amdgcn_mfma_f32_16x16x32_bf16(af[ai], bfr[bj], acc[ai][bj], 0, 0, 0);
    __syncthreads();
  }
#pragma unroll
  for (int ai = 0; ai < 4; ++ai)
#pragma unroll
    for (int bj = 0; bj < 4; ++bj) {
      const int col = dt * 128 + wc * 64 + bj * 16 + ll;
      const float bv = bias[col];
#pragma unroll
      for (int r = 0; r < 4; ++r) {
        const int row = qt * 128 + wr * 64 + ai * 16 + lg * 4 + r;
        OUT[(size_t)row * 512 + col] = acc[ai][bj][r] + bv;
      }
    }
}

extern "C" void kernel_launch(void* const* d_in, const int* in_sizes, int n_in,
                              void* d_out, int out_size, void* d_ws, size_t ws_size,
                              hipStream_t stream) {
  const float* x = (const float*)d_in[0];     // [8,2048,512]
  const float* Wqkv = (const float*)d_in[1];  // [512,1536]
  const float* Wout = (const float*)d_in[2];  // [512,512]
  const float* bout = (const float*)d_in[3];  // [512]
  float* out = (float*)d_out;                 // [8,2048,512] fp32

  unsigned short* qkvb = (unsigned short*)d_ws;        // 16384*1536 bf16 (q/k cols used)
  unsigned short* VT = qkvb + (size_t)16384 * 1536;    // 512*16384 bf16 = 16.8MB
  unsigned short* S = VT + (size_t)512 * 16384;        // 8*2048*2048 bf16 = 67.1MB
  unsigned short* xb = S;                              // bf16 X (dead before sgemm)
  unsigned short* WT = S + (size_t)16384 * 512;        // Wqkv^T scaled (dead before sgemm)
  // WoutT: written into dead S start after pvgemm (R15-validated ordering)
  float* part = out;                                   // [16384][32] f32 = 2MB scratch

  prep_xw<<<2096, 256, 0, stream>>>(x, xb, Wqkv, WT);
  gemm_qkv97<<<1536, 256, 0, stream>>>(xb, WT, qkvb, VT);
  sgemm256<<<512, 512, 0, stream>>>(qkvb, S, part);
  pvgemm97<<<512, 256, 0, stream>>>(S, VT, x, part, qkvb);
  transpose_wout<<<dim3(4, 4), 256, 0, stream>>>(Wout, (unsigned short*)S);  // S dead now
  gemm_out97<<<512, 256, 0, stream>>>(qkvb, (unsigned short*)S, bout, out);
}